// Round 1
// baseline (29647.964 us; speedup 1.0000x reference)
//
#include <hip/hip_runtime.h>

#define Bn 2048
#define Hn 1024
#define Ln 96
#define Vn 96

// ---------------------------------------------------------------------------
// L0: hcur[b,i] = tanh( hprev[b,:] . W[i,:] + x[b,t]*wih[i] + bih[i] + bhh[i] )
// Tile: BM=128 (b), BN=64 (i), BK=16. 256 threads, 8x4 micro-tile.
// LDS transposed: As[k][row] so inner reads are ds_read_b128.
// ---------------------------------------------------------------------------
__global__ __launch_bounds__(256, 2) void rnn_l0(
    const float* __restrict__ hprev, const float* __restrict__ W,
    const float* __restrict__ wih, const float* __restrict__ bih,
    const float* __restrict__ bhh, const float* __restrict__ x, int t,
    float* __restrict__ hcur)
{
    __shared__ float As[16][132];
    __shared__ float Ws[16][68];
    const int tid = threadIdx.x;
    const int bBase = blockIdx.y * 128;
    const int iBase = blockIdx.x * 64;
    const int ty = tid >> 4;       // 0..15 -> 8 b-rows each
    const int tx = tid & 15;       // 0..15 -> 4 i-cols each
    const int lr = tid >> 2;       // 0..63 (global-load row)
    const int lc = (tid & 3) << 2; // 0,4,8,12 (global-load col)

    const float* Arow0 = hprev + (size_t)(bBase + lr) * Hn + lc;
    const float* Arow1 = Arow0 + (size_t)64 * Hn;
    const float* Wrow  = W + (size_t)(iBase + lr) * Hn + lc;

    float4 pa0 = *(const float4*)(Arow0);
    float4 pa1 = *(const float4*)(Arow1);
    float4 pw  = *(const float4*)(Wrow);

    float acc[8][4];
#pragma unroll
    for (int m = 0; m < 8; ++m)
#pragma unroll
        for (int n = 0; n < 4; ++n) acc[m][n] = 0.f;

    for (int kt = 0; kt < Hn; kt += 16) {
        __syncthreads();
        As[lc+0][lr]    = pa0.x; As[lc+1][lr]    = pa0.y; As[lc+2][lr]    = pa0.z; As[lc+3][lr]    = pa0.w;
        As[lc+0][lr+64] = pa1.x; As[lc+1][lr+64] = pa1.y; As[lc+2][lr+64] = pa1.z; As[lc+3][lr+64] = pa1.w;
        Ws[lc+0][lr]    = pw.x;  Ws[lc+1][lr]    = pw.y;  Ws[lc+2][lr]    = pw.z;  Ws[lc+3][lr]    = pw.w;
        __syncthreads();
        if (kt + 16 < Hn) {
            pa0 = *(const float4*)(Arow0 + kt + 16);
            pa1 = *(const float4*)(Arow1 + kt + 16);
            pw  = *(const float4*)(Wrow  + kt + 16);
        }
#pragma unroll
        for (int k = 0; k < 16; ++k) {
            float4 a0 = *(const float4*)&As[k][ty*8];
            float4 a1 = *(const float4*)&As[k][ty*8+4];
            float4 w  = *(const float4*)&Ws[k][tx*4];
            float av[8] = {a0.x,a0.y,a0.z,a0.w,a1.x,a1.y,a1.z,a1.w};
            float wv[4] = {w.x,w.y,w.z,w.w};
#pragma unroll
            for (int m = 0; m < 8; ++m)
#pragma unroll
                for (int n = 0; n < 4; ++n)
                    acc[m][n] = fmaf(av[m], wv[n], acc[m][n]);
        }
    }

    const int i0 = iBase + tx * 4;
    float wih4[4], bb[4];
#pragma unroll
    for (int n = 0; n < 4; ++n) { wih4[n] = wih[i0+n]; bb[n] = bih[i0+n] + bhh[i0+n]; }
#pragma unroll
    for (int m = 0; m < 8; ++m) {
        int b = bBase + ty * 8 + m;
        float xv = x[b * Ln + t];
        float4 o;
        o.x = tanhf(fmaf(xv, wih4[0], acc[m][0] + bb[0]));
        o.y = tanhf(fmaf(xv, wih4[1], acc[m][1] + bb[1]));
        o.z = tanhf(fmaf(xv, wih4[2], acc[m][2] + bb[2]));
        o.w = tanhf(fmaf(xv, wih4[3], acc[m][3] + bb[3]));
        *(float4*)&hcur[(size_t)b * Hn + i0] = o;
    }
}

// ---------------------------------------------------------------------------
// L1: h1c[b,i] = tanh( h0c[b,:].Wi[i,:] + h1p[b,:].Wh[i,:] + bih[i] + bhh[i] )
// ---------------------------------------------------------------------------
__global__ __launch_bounds__(256, 2) void rnn_l1(
    const float* __restrict__ h0c, const float* __restrict__ h1p,
    const float* __restrict__ Wi, const float* __restrict__ Wh,
    const float* __restrict__ bih, const float* __restrict__ bhh,
    float* __restrict__ h1c)
{
    __shared__ float As0[16][132];
    __shared__ float As1[16][132];
    __shared__ float Ws0[16][68];
    __shared__ float Ws1[16][68];
    const int tid = threadIdx.x;
    const int bBase = blockIdx.y * 128;
    const int iBase = blockIdx.x * 64;
    const int ty = tid >> 4;
    const int tx = tid & 15;
    const int lr = tid >> 2;
    const int lc = (tid & 3) << 2;

    const float* A0r0 = h0c + (size_t)(bBase + lr) * Hn + lc;
    const float* A0r1 = A0r0 + (size_t)64 * Hn;
    const float* A1r0 = h1p + (size_t)(bBase + lr) * Hn + lc;
    const float* A1r1 = A1r0 + (size_t)64 * Hn;
    const float* Wir  = Wi + (size_t)(iBase + lr) * Hn + lc;
    const float* Whr  = Wh + (size_t)(iBase + lr) * Hn + lc;

    float4 p00 = *(const float4*)(A0r0);
    float4 p01 = *(const float4*)(A0r1);
    float4 p10 = *(const float4*)(A1r0);
    float4 p11 = *(const float4*)(A1r1);
    float4 pwi = *(const float4*)(Wir);
    float4 pwh = *(const float4*)(Whr);

    float acc[8][4];
#pragma unroll
    for (int m = 0; m < 8; ++m)
#pragma unroll
        for (int n = 0; n < 4; ++n) acc[m][n] = 0.f;

    for (int kt = 0; kt < Hn; kt += 16) {
        __syncthreads();
        As0[lc+0][lr]    = p00.x; As0[lc+1][lr]    = p00.y; As0[lc+2][lr]    = p00.z; As0[lc+3][lr]    = p00.w;
        As0[lc+0][lr+64] = p01.x; As0[lc+1][lr+64] = p01.y; As0[lc+2][lr+64] = p01.z; As0[lc+3][lr+64] = p01.w;
        As1[lc+0][lr]    = p10.x; As1[lc+1][lr]    = p10.y; As1[lc+2][lr]    = p10.z; As1[lc+3][lr]    = p10.w;
        As1[lc+0][lr+64] = p11.x; As1[lc+1][lr+64] = p11.y; As1[lc+2][lr+64] = p11.z; As1[lc+3][lr+64] = p11.w;
        Ws0[lc+0][lr] = pwi.x; Ws0[lc+1][lr] = pwi.y; Ws0[lc+2][lr] = pwi.z; Ws0[lc+3][lr] = pwi.w;
        Ws1[lc+0][lr] = pwh.x; Ws1[lc+1][lr] = pwh.y; Ws1[lc+2][lr] = pwh.z; Ws1[lc+3][lr] = pwh.w;
        __syncthreads();
        if (kt + 16 < Hn) {
            p00 = *(const float4*)(A0r0 + kt + 16);
            p01 = *(const float4*)(A0r1 + kt + 16);
            p10 = *(const float4*)(A1r0 + kt + 16);
            p11 = *(const float4*)(A1r1 + kt + 16);
            pwi = *(const float4*)(Wir  + kt + 16);
            pwh = *(const float4*)(Whr  + kt + 16);
        }
#pragma unroll
        for (int k = 0; k < 16; ++k) {
            float4 a0 = *(const float4*)&As0[k][ty*8];
            float4 a1 = *(const float4*)&As0[k][ty*8+4];
            float4 c0 = *(const float4*)&As1[k][ty*8];
            float4 c1 = *(const float4*)&As1[k][ty*8+4];
            float4 wi = *(const float4*)&Ws0[k][tx*4];
            float4 wh = *(const float4*)&Ws1[k][tx*4];
            float av[8] = {a0.x,a0.y,a0.z,a0.w,a1.x,a1.y,a1.z,a1.w};
            float cv[8] = {c0.x,c0.y,c0.z,c0.w,c1.x,c1.y,c1.z,c1.w};
            float wiv[4] = {wi.x,wi.y,wi.z,wi.w};
            float whv[4] = {wh.x,wh.y,wh.z,wh.w};
#pragma unroll
            for (int m = 0; m < 8; ++m)
#pragma unroll
                for (int n = 0; n < 4; ++n) {
                    acc[m][n] = fmaf(av[m], wiv[n], acc[m][n]);
                    acc[m][n] = fmaf(cv[m], whv[n], acc[m][n]);
                }
        }
    }

    const int i0 = iBase + tx * 4;
    float bb[4];
#pragma unroll
    for (int n = 0; n < 4; ++n) bb[n] = bih[i0+n] + bhh[i0+n];
#pragma unroll
    for (int m = 0; m < 8; ++m) {
        int b = bBase + ty * 8 + m;
        float4 o;
        o.x = tanhf(acc[m][0] + bb[0]);
        o.y = tanhf(acc[m][1] + bb[1]);
        o.z = tanhf(acc[m][2] + bb[2]);
        o.w = tanhf(acc[m][3] + bb[3]);
        *(float4*)&h1c[(size_t)b * Hn + i0] = o;
    }
}

// ---------------------------------------------------------------------------
// FC: out[b, t, v] = h1c[b,:] . fcW[v,:] + fcb[v]
// Tile: BM=64 (b), BN=96 (all v), BK=32. 256 threads, 4x6 micro-tile.
// ---------------------------------------------------------------------------
__global__ __launch_bounds__(256, 2) void fc_kernel(
    const float* __restrict__ h1c, const float* __restrict__ fcW,
    const float* __restrict__ fcb, int t, float* __restrict__ out)
{
    __shared__ float As[32][68];
    __shared__ float Ws[32][100];
    const int tid = threadIdx.x;
    const int bBase = blockIdx.x * 64;
    const int ty = tid >> 4;       // 0..15 -> 4 b-rows each
    const int tx = tid & 15;       // 0..15 -> 6 v-cols each
    const int r8 = tid >> 3;       // 0..31
    const int c8 = (tid & 7) << 2; // 0,4,...,28

    const float* Ab = h1c + (size_t)bBase * Hn;

    float4 pa0 = *(const float4*)&Ab[(size_t)(r8)      * Hn + c8];
    float4 pa1 = *(const float4*)&Ab[(size_t)(r8 + 32) * Hn + c8];
    float4 pw0 = *(const float4*)&fcW[(size_t)(r8)      * Hn + c8];
    float4 pw1 = *(const float4*)&fcW[(size_t)(r8 + 32) * Hn + c8];
    float4 pw2 = *(const float4*)&fcW[(size_t)(r8 + 64) * Hn + c8];

    float acc[4][6];
#pragma unroll
    for (int m = 0; m < 4; ++m)
#pragma unroll
        for (int n = 0; n < 6; ++n) acc[m][n] = 0.f;

    for (int kt = 0; kt < Hn; kt += 32) {
        __syncthreads();
        As[c8+0][r8]    = pa0.x; As[c8+1][r8]    = pa0.y; As[c8+2][r8]    = pa0.z; As[c8+3][r8]    = pa0.w;
        As[c8+0][r8+32] = pa1.x; As[c8+1][r8+32] = pa1.y; As[c8+2][r8+32] = pa1.z; As[c8+3][r8+32] = pa1.w;
        Ws[c8+0][r8]    = pw0.x; Ws[c8+1][r8]    = pw0.y; Ws[c8+2][r8]    = pw0.z; Ws[c8+3][r8]    = pw0.w;
        Ws[c8+0][r8+32] = pw1.x; Ws[c8+1][r8+32] = pw1.y; Ws[c8+2][r8+32] = pw1.z; Ws[c8+3][r8+32] = pw1.w;
        Ws[c8+0][r8+64] = pw2.x; Ws[c8+1][r8+64] = pw2.y; Ws[c8+2][r8+64] = pw2.z; Ws[c8+3][r8+64] = pw2.w;
        __syncthreads();
        if (kt + 32 < Hn) {
            pa0 = *(const float4*)&Ab[(size_t)(r8)      * Hn + kt + 32 + c8];
            pa1 = *(const float4*)&Ab[(size_t)(r8 + 32) * Hn + kt + 32 + c8];
            pw0 = *(const float4*)&fcW[(size_t)(r8)      * Hn + kt + 32 + c8];
            pw1 = *(const float4*)&fcW[(size_t)(r8 + 32) * Hn + kt + 32 + c8];
            pw2 = *(const float4*)&fcW[(size_t)(r8 + 64) * Hn + kt + 32 + c8];
        }
#pragma unroll
        for (int k = 0; k < 32; ++k) {
            float4 a = *(const float4*)&As[k][ty*4];
            float2 w01 = *(const float2*)&Ws[k][tx*6];
            float2 w23 = *(const float2*)&Ws[k][tx*6+2];
            float2 w45 = *(const float2*)&Ws[k][tx*6+4];
            float av[4] = {a.x, a.y, a.z, a.w};
            float wv[6] = {w01.x, w01.y, w23.x, w23.y, w45.x, w45.y};
#pragma unroll
            for (int m = 0; m < 4; ++m)
#pragma unroll
                for (int n = 0; n < 6; ++n)
                    acc[m][n] = fmaf(av[m], wv[n], acc[m][n]);
        }
    }

    const int v0 = tx * 6;
    float bv[6];
#pragma unroll
    for (int n = 0; n < 6; ++n) bv[n] = fcb[v0 + n];
#pragma unroll
    for (int m = 0; m < 4; ++m) {
        int b = bBase + ty * 4 + m;
        size_t o = (size_t)b * (Ln * Vn) + (size_t)t * Vn + v0;
#pragma unroll
        for (int n = 0; n < 6; ++n) out[o + n] = acc[m][n] + bv[n];
    }
}

// ---------------------------------------------------------------------------
// Sequential probability adjustment scan. One wave per batch row.
// jnp.argmax = first occurrence of max -> tie-break to LOWER index.
// ---------------------------------------------------------------------------
__device__ __forceinline__ int wave_argmax(float v0, float v1, int lane)
{
    float bv = v0;
    int bi = lane;
    if (v1 > bv) { bv = v1; bi = 64 + lane; }
#pragma unroll
    for (int off = 32; off > 0; off >>= 1) {
        float ov = __shfl_xor(bv, off);
        int oi = __shfl_xor(bi, off);
        if (ov > bv || (ov == bv && oi < bi)) { bv = ov; bi = oi; }
    }
    return bi;
}

__global__ __launch_bounds__(256) void adjust_kernel(float* __restrict__ out)
{
    const int gtid = blockIdx.x * 256 + threadIdx.x;
    const int b = gtid >> 6;
    const int lane = threadIdx.x & 63;
    if (b >= Bn) return;
    float* row = out + (size_t)b * (Ln * Vn);

    // t = 0: unadjusted; carry its argmax.
    float v0 = row[lane];
    float v1 = (lane < 32) ? row[64 + lane] : -1e30f;
    int prev_arg = wave_argmax(v0, v1, lane);

    for (int t = 1; t < Ln; ++t) {
        float* r = row + t * Vn;
        v0 = r[lane];
        v1 = (lane < 32) ? r[64 + lane] : -1e30f;
        int cur_arg = wave_argmax(v0, v1, lane);
        bool cond_u = (prev_arg == 0) && (cur_arg != 1);
        if (cond_u && lane == 1) v0 += 0.5f;
        bool cond_q = (t == Ln - 1) && (cur_arg == 0);
        if (cond_q && lane == 0) v0 -= 0.5f;
        r[lane] = v0;
        if (lane < 32) r[64 + lane] = v1;
        prev_arg = wave_argmax(v0, v1, lane);  // argmax of ADJUSTED row carries
    }
}

// ---------------------------------------------------------------------------
extern "C" void kernel_launch(void* const* d_in, const int* in_sizes, int n_in,
                              void* d_out, int out_size, void* d_ws, size_t ws_size,
                              hipStream_t stream)
{
    const float* x    = (const float*)d_in[0];
    const float* w0ih = (const float*)d_in[1];   // [H,1] -> vector
    const float* W0   = (const float*)d_in[2];   // [H,H]
    const float* b0i  = (const float*)d_in[3];
    const float* b0h  = (const float*)d_in[4];
    const float* W1i  = (const float*)d_in[5];   // [H,H]
    const float* W1h  = (const float*)d_in[6];   // [H,H]
    const float* b1i  = (const float*)d_in[7];
    const float* b1h  = (const float*)d_in[8];
    const float* fcW  = (const float*)d_in[9];   // [V,H]
    const float* fcb  = (const float*)d_in[10];
    float* out = (float*)d_out;

    const size_t BH = (size_t)Bn * Hn;
    // ws layout: [h0A][h1A][h0B][h1B], final state lands in A (t=95 writes cur=0)
    float* h0[2] = { (float*)d_ws,          (float*)d_ws + 2 * BH };
    float* h1[2] = { (float*)d_ws + BH,     (float*)d_ws + 3 * BH };

    hipMemsetAsync(d_ws, 0, 2 * BH * sizeof(float), stream);  // zero h0A,h1A

    dim3 blk(256);
    dim3 gG(16, 16);   // (H/64, B/128)
    int prev = 0, cur = 1;
    for (int t = 0; t < Ln; ++t) {
        rnn_l0<<<gG, blk, 0, stream>>>(h0[prev], W0, w0ih, b0i, b0h, x, t, h0[cur]);
        rnn_l1<<<gG, blk, 0, stream>>>(h0[cur], h1[prev], W1i, W1h, b1i, b1h, h1[cur]);
        fc_kernel<<<dim3(32), blk, 0, stream>>>(h1[cur], fcW, fcb, t, out);
        prev ^= 1; cur ^= 1;
    }

    adjust_kernel<<<dim3(512), blk, 0, stream>>>(out);

    // hidden output: [h0_final][h1_final] contiguous at ws offset 0
    hipMemcpyAsync(out + (size_t)Bn * Ln * Vn, d_ws, 2 * BH * sizeof(float),
                   hipMemcpyDeviceToDevice, stream);
}

// Round 2
// 7089.458 us; speedup vs baseline: 4.1820x; 4.1820x over previous
//
#include <hip/hip_runtime.h>

#define Bn 2048
#define Hn 1024
#define Ln 96
#define Vn 96

typedef short bf16x8 __attribute__((ext_vector_type(8)));
typedef float f32x4 __attribute__((ext_vector_type(4)));

__device__ __forceinline__ void async16(const void* g, void* l)
{
    __builtin_amdgcn_global_load_lds(
        (const __attribute__((address_space(1))) void*)g,
        (__attribute__((address_space(3))) void*)l, 16, 0, 0);
}

__device__ __forceinline__ unsigned short f2bf(float f)
{
    unsigned u = __float_as_uint(f);
    u += 0x7fff + ((u >> 16) & 1);          // round-to-nearest-even
    return (unsigned short)(u >> 16);
}

__device__ __forceinline__ float bf2f(unsigned short s)
{
    return __uint_as_float(((unsigned)s) << 16);
}

__device__ __forceinline__ float fast_tanh(float x)
{
    float e = __expf(2.0f * x);
    return 1.0f - __fdividef(2.0f, e + 1.0f);
}

// ---------------------------------------------------------------------------
// L0: hcur = tanh(hprev @ W^T + x_t*wih + bih + bhh).  A,W bf16; epilogue f32.
// 128 thr = 2 waves; BM=128 (wave-stacked), BN=64, BK=32; 64x64 wave tile.
// ---------------------------------------------------------------------------
__global__ __launch_bounds__(128) void rnn_l0(
    const unsigned short* __restrict__ hprev,  // [B][H] bf16
    const unsigned short* __restrict__ W,      // [H][H] bf16
    const float* __restrict__ wih, const float* __restrict__ bih,
    const float* __restrict__ bhh, const float* __restrict__ x, int t,
    unsigned short* __restrict__ hcur)
{
    __shared__ unsigned short As[2][128 * 32];
    __shared__ unsigned short Bs[2][64 * 32];
    const int tid = threadIdx.x;
    const int lane = tid & 63;
    const int wave = tid >> 6;
    const int bBase = blockIdx.y * 128;
    const int iBase = blockIdx.x * 64;
    const int srow = lane >> 2;
    const int scol = (lane & 3) * 8;
    const int lr = lane & 15;
    const int lq = lane >> 4;
    const int mw = wave * 64;

    f32x4 acc[4][4];
#pragma unroll
    for (int i = 0; i < 4; ++i)
#pragma unroll
        for (int j = 0; j < 4; ++j) acc[i][j] = (f32x4){0.f, 0.f, 0.f, 0.f};

#define STAGE_L0(buf, kt)                                                            \
    do {                                                                             \
        if (wave == 0) {                                                             \
            _Pragma("unroll")                                                        \
            for (int c = 0; c < 6; ++c)                                              \
                async16(hprev + (size_t)(bBase + c * 16 + srow) * Hn + (kt) + scol,  \
                        &As[buf][c * 512]);                                          \
        } else {                                                                     \
            _Pragma("unroll")                                                        \
            for (int c = 6; c < 8; ++c)                                              \
                async16(hprev + (size_t)(bBase + c * 16 + srow) * Hn + (kt) + scol,  \
                        &As[buf][c * 512]);                                          \
            _Pragma("unroll")                                                        \
            for (int c = 0; c < 4; ++c)                                              \
                async16(W + (size_t)(iBase + c * 16 + srow) * Hn + (kt) + scol,      \
                        &Bs[buf][c * 512]);                                          \
        }                                                                            \
    } while (0)

    STAGE_L0(0, 0);
    int buf = 0;
    for (int kt = 0; kt < Hn; kt += 32) {
        __syncthreads();
        if (kt + 32 < Hn) STAGE_L0(buf ^ 1, kt + 32);
        bf16x8 a[4], b[4];
#pragma unroll
        for (int i = 0; i < 4; ++i) {
            a[i] = *(const bf16x8*)&As[buf][(mw + i * 16 + lr) * 32 + lq * 8];
            b[i] = *(const bf16x8*)&Bs[buf][(i * 16 + lr) * 32 + lq * 8];
        }
#pragma unroll
        for (int mt = 0; mt < 4; ++mt)
#pragma unroll
            for (int nt = 0; nt < 4; ++nt)
                acc[mt][nt] = __builtin_amdgcn_mfma_f32_16x16x32_bf16(
                    a[mt], b[nt], acc[mt][nt], 0, 0, 0);
        buf ^= 1;
    }

    float wvs[4], bs[4];
#pragma unroll
    for (int nt = 0; nt < 4; ++nt) {
        int n = iBase + nt * 16 + lr;
        wvs[nt] = wih[n];
        bs[nt] = bih[n] + bhh[n];
    }
#pragma unroll
    for (int mt = 0; mt < 4; ++mt) {
#pragma unroll
        for (int r = 0; r < 4; ++r) {
            int bb = bBase + mw + mt * 16 + lq * 4 + r;
            float xv = x[bb * Ln + t];
#pragma unroll
            for (int nt = 0; nt < 4; ++nt) {
                int n = iBase + nt * 16 + lr;
                float v = acc[mt][nt][r] + xv * wvs[nt] + bs[nt];
                hcur[(size_t)bb * Hn + n] = f2bf(fast_tanh(v));
            }
        }
    }
}

// ---------------------------------------------------------------------------
// L1 dual-GEMM: h1c = tanh(h0c @ Wi^T + h1p @ Wh^T + bih + bhh)
// ---------------------------------------------------------------------------
__global__ __launch_bounds__(128) void rnn_l1(
    const unsigned short* __restrict__ h0c, const unsigned short* __restrict__ h1p,
    const unsigned short* __restrict__ Wi, const unsigned short* __restrict__ Wh,
    const float* __restrict__ bih, const float* __restrict__ bhh,
    unsigned short* __restrict__ h1c)
{
    __shared__ unsigned short As0[2][128 * 32];
    __shared__ unsigned short As1[2][128 * 32];
    __shared__ unsigned short Bs0[2][64 * 32];
    __shared__ unsigned short Bs1[2][64 * 32];
    const int tid = threadIdx.x;
    const int lane = tid & 63;
    const int wave = tid >> 6;
    const int bBase = blockIdx.y * 128;
    const int iBase = blockIdx.x * 64;
    const int srow = lane >> 2;
    const int scol = (lane & 3) * 8;
    const int lr = lane & 15;
    const int lq = lane >> 4;
    const int mw = wave * 64;

    // wave 0 stages A0+B0, wave 1 stages A1+B1 (uniform per-wave pointers)
    const unsigned short* Aw = (wave == 0) ? h0c : h1p;
    const unsigned short* Ww = (wave == 0) ? Wi : Wh;

    f32x4 acc[4][4];
#pragma unroll
    for (int i = 0; i < 4; ++i)
#pragma unroll
        for (int j = 0; j < 4; ++j) acc[i][j] = (f32x4){0.f, 0.f, 0.f, 0.f};

#define STAGE_L1(buf, kt)                                                        \
    do {                                                                         \
        unsigned short* Adst = (wave == 0) ? As0[buf] : As1[buf];                \
        unsigned short* Bdst = (wave == 0) ? Bs0[buf] : Bs1[buf];                \
        _Pragma("unroll")                                                        \
        for (int c = 0; c < 8; ++c)                                              \
            async16(Aw + (size_t)(bBase + c * 16 + srow) * Hn + (kt) + scol,     \
                    Adst + c * 512);                                             \
        _Pragma("unroll")                                                        \
        for (int c = 0; c < 4; ++c)                                              \
            async16(Ww + (size_t)(iBase + c * 16 + srow) * Hn + (kt) + scol,     \
                    Bdst + c * 512);                                             \
    } while (0)

    STAGE_L1(0, 0);
    int buf = 0;
    for (int kt = 0; kt < Hn; kt += 32) {
        __syncthreads();
        if (kt + 32 < Hn) STAGE_L1(buf ^ 1, kt + 32);
        bf16x8 a0[4], a1[4], b0[4], b1[4];
#pragma unroll
        for (int i = 0; i < 4; ++i) {
            a0[i] = *(const bf16x8*)&As0[buf][(mw + i * 16 + lr) * 32 + lq * 8];
            a1[i] = *(const bf16x8*)&As1[buf][(mw + i * 16 + lr) * 32 + lq * 8];
            b0[i] = *(const bf16x8*)&Bs0[buf][(i * 16 + lr) * 32 + lq * 8];
            b1[i] = *(const bf16x8*)&Bs1[buf][(i * 16 + lr) * 32 + lq * 8];
        }
#pragma unroll
        for (int mt = 0; mt < 4; ++mt)
#pragma unroll
            for (int nt = 0; nt < 4; ++nt) {
                acc[mt][nt] = __builtin_amdgcn_mfma_f32_16x16x32_bf16(
                    a0[mt], b0[nt], acc[mt][nt], 0, 0, 0);
                acc[mt][nt] = __builtin_amdgcn_mfma_f32_16x16x32_bf16(
                    a1[mt], b1[nt], acc[mt][nt], 0, 0, 0);
            }
        buf ^= 1;
    }

    float bs[4];
#pragma unroll
    for (int nt = 0; nt < 4; ++nt) {
        int n = iBase + nt * 16 + lr;
        bs[nt] = bih[n] + bhh[n];
    }
#pragma unroll
    for (int mt = 0; mt < 4; ++mt) {
#pragma unroll
        for (int r = 0; r < 4; ++r) {
            int bb = bBase + mw + mt * 16 + lq * 4 + r;
#pragma unroll
            for (int nt = 0; nt < 4; ++nt) {
                int n = iBase + nt * 16 + lr;
                h1c[(size_t)bb * Hn + n] = f2bf(fast_tanh(acc[mt][nt][r] + bs[nt]));
            }
        }
    }
}

// ---------------------------------------------------------------------------
// FC: out[b,t,v] = h1c[b,:] . fcW[v,:] + fcb[v].  BM=128, BN=96 (all V).
// ---------------------------------------------------------------------------
__global__ __launch_bounds__(128) void fc_kernel(
    const unsigned short* __restrict__ h1c, const unsigned short* __restrict__ fcW,
    const float* __restrict__ fcb, int t, float* __restrict__ out)
{
    __shared__ unsigned short As[2][128 * 32];
    __shared__ unsigned short Bs[2][96 * 32];
    const int tid = threadIdx.x;
    const int lane = tid & 63;
    const int wave = tid >> 6;
    const int bBase = blockIdx.x * 128;
    const int srow = lane >> 2;
    const int scol = (lane & 3) * 8;
    const int lr = lane & 15;
    const int lq = lane >> 4;
    const int mw = wave * 64;

    f32x4 acc[4][6];
#pragma unroll
    for (int i = 0; i < 4; ++i)
#pragma unroll
        for (int j = 0; j < 6; ++j) acc[i][j] = (f32x4){0.f, 0.f, 0.f, 0.f};

#define STAGE_FC(buf, kt)                                                        \
    do {                                                                         \
        if (wave == 0) {                                                         \
            _Pragma("unroll")                                                    \
            for (int c = 0; c < 8; ++c)                                          \
                async16(h1c + (size_t)(bBase + c * 16 + srow) * Hn + (kt) + scol,\
                        &As[buf][c * 512]);                                      \
        } else {                                                                 \
            _Pragma("unroll")                                                    \
            for (int c = 0; c < 6; ++c)                                          \
                async16(fcW + (size_t)(c * 16 + srow) * Hn + (kt) + scol,        \
                        &Bs[buf][c * 512]);                                      \
        }                                                                        \
    } while (0)

    STAGE_FC(0, 0);
    int buf = 0;
    for (int kt = 0; kt < Hn; kt += 32) {
        __syncthreads();
        if (kt + 32 < Hn) STAGE_FC(buf ^ 1, kt + 32);
        bf16x8 a[4], b[6];
#pragma unroll
        for (int i = 0; i < 4; ++i)
            a[i] = *(const bf16x8*)&As[buf][(mw + i * 16 + lr) * 32 + lq * 8];
#pragma unroll
        for (int i = 0; i < 6; ++i)
            b[i] = *(const bf16x8*)&Bs[buf][(i * 16 + lr) * 32 + lq * 8];
#pragma unroll
        for (int mt = 0; mt < 4; ++mt)
#pragma unroll
            for (int nt = 0; nt < 6; ++nt)
                acc[mt][nt] = __builtin_amdgcn_mfma_f32_16x16x32_bf16(
                    a[mt], b[nt], acc[mt][nt], 0, 0, 0);
        buf ^= 1;
    }

#pragma unroll
    for (int mt = 0; mt < 4; ++mt) {
#pragma unroll
        for (int r = 0; r < 4; ++r) {
            int bb = bBase + mw + mt * 16 + lq * 4 + r;
            size_t o = (size_t)bb * (Ln * Vn) + (size_t)t * Vn;
#pragma unroll
            for (int nt = 0; nt < 6; ++nt) {
                int v = nt * 16 + lr;
                out[o + v] = acc[mt][nt][r] + fcb[v];
            }
        }
    }
}

// ---------------------------------------------------------------------------
__global__ void f32_to_bf16(const float* __restrict__ in,
                            unsigned short* __restrict__ out, int n)
{
    int i = blockIdx.x * blockDim.x + threadIdx.x;
    int stride = gridDim.x * blockDim.x;
    for (; i < n; i += stride) out[i] = f2bf(in[i]);
}

__global__ void hidden_out(const unsigned short* __restrict__ h0,
                           const unsigned short* __restrict__ h1,
                           float* __restrict__ out)
{
    int i = blockIdx.x * 256 + threadIdx.x;
    out[i] = bf2f(h0[i]);
    out[(size_t)Bn * Hn + i] = bf2f(h1[i]);
}

// ---------------------------------------------------------------------------
// Sequential probability adjustment (verified round 1). One wave per batch row.
// ---------------------------------------------------------------------------
__device__ __forceinline__ int wave_argmax(float v0, float v1, int lane)
{
    float bv = v0;
    int bi = lane;
    if (v1 > bv) { bv = v1; bi = 64 + lane; }
#pragma unroll
    for (int off = 32; off > 0; off >>= 1) {
        float ov = __shfl_xor(bv, off);
        int oi = __shfl_xor(bi, off);
        if (ov > bv || (ov == bv && oi < bi)) { bv = ov; bi = oi; }
    }
    return bi;
}

__global__ __launch_bounds__(256) void adjust_kernel(float* __restrict__ out)
{
    const int gtid = blockIdx.x * 256 + threadIdx.x;
    const int b = gtid >> 6;
    const int lane = threadIdx.x & 63;
    if (b >= Bn) return;
    float* row = out + (size_t)b * (Ln * Vn);

    float v0 = row[lane];
    float v1 = (lane < 32) ? row[64 + lane] : -1e30f;
    int prev_arg = wave_argmax(v0, v1, lane);

    for (int t = 1; t < Ln; ++t) {
        float* r = row + t * Vn;
        v0 = r[lane];
        v1 = (lane < 32) ? r[64 + lane] : -1e30f;
        int cur_arg = wave_argmax(v0, v1, lane);
        bool cond_u = (prev_arg == 0) && (cur_arg != 1);
        if (cond_u && lane == 1) v0 += 0.5f;
        bool cond_q = (t == Ln - 1) && (cur_arg == 0);
        if (cond_q && lane == 0) v0 -= 0.5f;
        r[lane] = v0;
        if (lane < 32) r[64 + lane] = v1;
        prev_arg = wave_argmax(v0, v1, lane);
    }
}

// ---------------------------------------------------------------------------
extern "C" void kernel_launch(void* const* d_in, const int* in_sizes, int n_in,
                              void* d_out, int out_size, void* d_ws, size_t ws_size,
                              hipStream_t stream)
{
    const float* x    = (const float*)d_in[0];
    const float* w0ih = (const float*)d_in[1];
    const float* W0   = (const float*)d_in[2];
    const float* b0i  = (const float*)d_in[3];
    const float* b0h  = (const float*)d_in[4];
    const float* W1i  = (const float*)d_in[5];
    const float* W1h  = (const float*)d_in[6];
    const float* b1i  = (const float*)d_in[7];
    const float* b1h  = (const float*)d_in[8];
    const float* fcW  = (const float*)d_in[9];
    const float* fcb  = (const float*)d_in[10];
    float* out = (float*)d_out;

    const size_t HH = (size_t)Hn * Hn;          // 1M
    const size_t BH = (size_t)Bn * Hn;          // 2M
    unsigned short* ws = (unsigned short*)d_ws;
    unsigned short* W0b  = ws;                  // [0, 1M)
    unsigned short* W1ib = ws + HH;             // [1M, 2M)
    unsigned short* W1hb = ws + 2 * HH;         // [2M, 3M)
    unsigned short* fcWb = ws + 3 * HH;         // [3M, 3M+96K)
    unsigned short* h0[2] = { ws + 4 * HH,  ws + 4 * HH + BH };   // [4M,8M)
    unsigned short* h1[2] = { ws + 4 * HH + 2 * BH, ws + 4 * HH + 3 * BH }; // [8M,12M)

    // zero initial hidden states (bf16 zero == 0x0000)
    hipMemsetAsync(h0[0], 0, BH * sizeof(unsigned short), stream);
    hipMemsetAsync(h1[0], 0, BH * sizeof(unsigned short), stream);

    // weight conversion f32 -> bf16
    f32_to_bf16<<<dim3(512), dim3(256), 0, stream>>>(W0,  W0b,  (int)HH);
    f32_to_bf16<<<dim3(512), dim3(256), 0, stream>>>(W1i, W1ib, (int)HH);
    f32_to_bf16<<<dim3(512), dim3(256), 0, stream>>>(W1h, W1hb, (int)HH);
    f32_to_bf16<<<dim3(64),  dim3(256), 0, stream>>>(fcW, fcWb, Vn * Hn);

    dim3 gG(16, 16);  // (H/64, B/128)
    int prev = 0, cur = 1, fin = 0;
    for (int t = 0; t < Ln; ++t) {
        rnn_l0<<<gG, dim3(128), 0, stream>>>(h0[prev], W0b, w0ih, b0i, b0h, x, t, h0[cur]);
        rnn_l1<<<gG, dim3(128), 0, stream>>>(h0[cur], h1[prev], W1ib, W1hb, b1i, b1h, h1[cur]);
        fc_kernel<<<dim3(16), dim3(128), 0, stream>>>(h1[cur], fcWb, fcb, t, out);
        fin = cur;
        prev ^= 1; cur ^= 1;
    }

    adjust_kernel<<<dim3(512), dim3(256), 0, stream>>>(out);

    hidden_out<<<dim3((int)(BH / 256)), dim3(256), 0, stream>>>(
        h0[fin], h1[fin], out + (size_t)Bn * Ln * Vn);
}

// Round 3
// 3923.274 us; speedup vs baseline: 7.5569x; 1.8070x over previous
//
#include <hip/hip_runtime.h>

#define Bn 2048
#define Hn 1024
#define Ln 96
#define Vn 96

typedef short bf16x8 __attribute__((ext_vector_type(8)));
typedef float f32x4 __attribute__((ext_vector_type(4)));

__device__ __forceinline__ void async16(const void* g, void* l)
{
    __builtin_amdgcn_global_load_lds(
        (const __attribute__((address_space(1))) void*)g,
        (__attribute__((address_space(3))) void*)l, 16, 0, 0);
}

__device__ __forceinline__ unsigned short f2bf(float f)
{
    unsigned u = __float_as_uint(f);
    u += 0x7fff + ((u >> 16) & 1);          // round-to-nearest-even
    return (unsigned short)(u >> 16);
}

__device__ __forceinline__ float bf2f(unsigned short s)
{
    return __uint_as_float(((unsigned)s) << 16);
}

__device__ __forceinline__ float fast_tanh(float x)
{
    float e = __expf(2.0f * x);
    return 1.0f - __fdividef(2.0f, e + 1.0f);
}

// ---------------------------------------------------------------------------
// Fused step kernel, launch index s (0..97):
//   blocks [0,512)    : L1(t=s-1)  h1(t) = tanh(h0(t)Wi^T + h1(t-1)Wh^T + b)
//   blocks [512,1024) : L0(t=s)    h0(t) = tanh(h0(t-1)W0^T + x_t*wih + b)
//   blocks [1024,1056): FC(t=s-2)  out(t) = h1(t) fcW^T + fcb
// All three roles only read buffers produced in PREVIOUS launches -> no
// intra-launch ordering needed. Each block: 2 independent 64x64-tile GEMM
// waves (split-K / dual-matrix), f32 LDS reduce, epilogue by wave 0.
// LDS: A = 2 waves x dbuf x 64x32 bf16 (16 KB), B = 2 x dbuf x 96x32 (24 KB)
//      reduce f32 aliases the B region (<=24 KB). Total 40 KB -> 4 blk/CU.
// ---------------------------------------------------------------------------
__global__ __launch_bounds__(128, 2) void fused_step(
    int s,
    const unsigned short* __restrict__ H0rd, unsigned short* __restrict__ H0wr,
    const unsigned short* __restrict__ H1rd, unsigned short* __restrict__ H1wr,
    const unsigned short* __restrict__ W0b,
    const unsigned short* __restrict__ W1ib, const unsigned short* __restrict__ W1hb,
    const unsigned short* __restrict__ fcWb,
    const float* __restrict__ w0ih,
    const float* __restrict__ b0i, const float* __restrict__ b0h,
    const float* __restrict__ b1i, const float* __restrict__ b1h,
    const float* __restrict__ fcb, const float* __restrict__ x,
    float* __restrict__ out)
{
    __shared__ __align__(16) unsigned short smem[20480];   // 40 KB
    const int tid = threadIdx.x;
    const int lane = tid & 63;
    const int wave = tid >> 6;
    const int srow = lane >> 2;        // staging row within 16-row chunk
    const int scol = (lane & 3) * 8;   // staging col (bf16 elems)
    const int lr = lane & 15;
    const int lq = lane >> 4;
    unsigned short* Al = smem + wave * 4096;           // + buf*2048
    unsigned short* Bl = smem + 8192 + wave * 6144;    // + buf*3072
    float* red = (float*)(smem + 8192);                // 24 KB reduce area
    const int bid = blockIdx.x;

    if (bid < 512) {
        // ================= L1(t = s-1), dual GEMM split across waves ======
        if (s < 1 || s > 96) return;
        const int bBase = (bid >> 4) * 64;
        const int iBase = (bid & 15) * 64;
        const unsigned short* Ag = wave ? H1rd : H0rd;
        const unsigned short* Bg = wave ? W1hb : W1ib;

        f32x4 acc[4][4];
#pragma unroll
        for (int i = 0; i < 4; ++i)
#pragma unroll
            for (int j = 0; j < 4; ++j) acc[i][j] = (f32x4){0.f, 0.f, 0.f, 0.f};

#pragma unroll
        for (int c = 0; c < 4; ++c) {
            async16(Ag + (size_t)(bBase + c * 16 + srow) * Hn + scol, Al + c * 512);
            async16(Bg + (size_t)(iBase + c * 16 + srow) * Hn + scol, Bl + c * 512);
        }
        int buf = 0;
        for (int it = 0; it < 32; ++it) {
            __syncthreads();
            if (it + 1 < 32) {
                const int kt = (it + 1) * 32;
#pragma unroll
                for (int c = 0; c < 4; ++c) {
                    async16(Ag + (size_t)(bBase + c * 16 + srow) * Hn + kt + scol,
                            Al + (buf ^ 1) * 2048 + c * 512);
                    async16(Bg + (size_t)(iBase + c * 16 + srow) * Hn + kt + scol,
                            Bl + (buf ^ 1) * 3072 + c * 512);
                }
            }
            bf16x8 a[4], b[4];
#pragma unroll
            for (int i = 0; i < 4; ++i) {
                a[i] = *(const bf16x8*)(Al + buf * 2048 + (i * 16 + lr) * 32 + lq * 8);
                b[i] = *(const bf16x8*)(Bl + buf * 3072 + (i * 16 + lr) * 32 + lq * 8);
            }
#pragma unroll
            for (int mt = 0; mt < 4; ++mt)
#pragma unroll
                for (int nt = 0; nt < 4; ++nt)
                    acc[mt][nt] = __builtin_amdgcn_mfma_f32_16x16x32_bf16(
                        a[mt], b[nt], acc[mt][nt], 0, 0, 0);
            buf ^= 1;
        }
        __syncthreads();
        if (wave == 1) {
#pragma unroll
            for (int mt = 0; mt < 4; ++mt)
#pragma unroll
                for (int nt = 0; nt < 4; ++nt)
#pragma unroll
                    for (int r = 0; r < 4; ++r)
                        red[(mt * 16 + lq * 4 + r) * 64 + nt * 16 + lr] = acc[mt][nt][r];
        }
        __syncthreads();
        if (wave == 0) {
#pragma unroll
            for (int nt = 0; nt < 4; ++nt) {
                const int n = iBase + nt * 16 + lr;
                const float bs = b1i[n] + b1h[n];
#pragma unroll
                for (int mt = 0; mt < 4; ++mt)
#pragma unroll
                    for (int r = 0; r < 4; ++r) {
                        const int row = mt * 16 + lq * 4 + r;
                        float v = acc[mt][nt][r] + red[row * 64 + nt * 16 + lr] + bs;
                        H1wr[(size_t)(bBase + row) * Hn + n] = f2bf(fast_tanh(v));
                    }
            }
        }
    } else if (bid < 1024) {
        // ================= L0(t = s), split-K across waves ================
        if (s > 95) return;
        const int idx = bid - 512;
        const int bBase = (idx >> 4) * 64;
        const int iBase = (idx & 15) * 64;
        const int k0 = wave * 512;
        const unsigned short* Ag = H0rd;
        const unsigned short* Bg = W0b;

        f32x4 acc[4][4];
#pragma unroll
        for (int i = 0; i < 4; ++i)
#pragma unroll
            for (int j = 0; j < 4; ++j) acc[i][j] = (f32x4){0.f, 0.f, 0.f, 0.f};

#pragma unroll
        for (int c = 0; c < 4; ++c) {
            async16(Ag + (size_t)(bBase + c * 16 + srow) * Hn + k0 + scol, Al + c * 512);
            async16(Bg + (size_t)(iBase + c * 16 + srow) * Hn + k0 + scol, Bl + c * 512);
        }
        int buf = 0;
        for (int it = 0; it < 16; ++it) {
            __syncthreads();
            if (it + 1 < 16) {
                const int kt = k0 + (it + 1) * 32;
#pragma unroll
                for (int c = 0; c < 4; ++c) {
                    async16(Ag + (size_t)(bBase + c * 16 + srow) * Hn + kt + scol,
                            Al + (buf ^ 1) * 2048 + c * 512);
                    async16(Bg + (size_t)(iBase + c * 16 + srow) * Hn + kt + scol,
                            Bl + (buf ^ 1) * 3072 + c * 512);
                }
            }
            bf16x8 a[4], b[4];
#pragma unroll
            for (int i = 0; i < 4; ++i) {
                a[i] = *(const bf16x8*)(Al + buf * 2048 + (i * 16 + lr) * 32 + lq * 8);
                b[i] = *(const bf16x8*)(Bl + buf * 3072 + (i * 16 + lr) * 32 + lq * 8);
            }
#pragma unroll
            for (int mt = 0; mt < 4; ++mt)
#pragma unroll
                for (int nt = 0; nt < 4; ++nt)
                    acc[mt][nt] = __builtin_amdgcn_mfma_f32_16x16x32_bf16(
                        a[mt], b[nt], acc[mt][nt], 0, 0, 0);
            buf ^= 1;
        }
        __syncthreads();
        if (wave == 1) {
#pragma unroll
            for (int mt = 0; mt < 4; ++mt)
#pragma unroll
                for (int nt = 0; nt < 4; ++nt)
#pragma unroll
                    for (int r = 0; r < 4; ++r)
                        red[(mt * 16 + lq * 4 + r) * 64 + nt * 16 + lr] = acc[mt][nt][r];
        }
        __syncthreads();
        if (wave == 0) {
#pragma unroll
            for (int nt = 0; nt < 4; ++nt) {
                const int n = iBase + nt * 16 + lr;
                const float wv = w0ih[n];
                const float bs = b0i[n] + b0h[n];
#pragma unroll
                for (int mt = 0; mt < 4; ++mt)
#pragma unroll
                    for (int r = 0; r < 4; ++r) {
                        const int row = mt * 16 + lq * 4 + r;
                        const int bb = bBase + row;
                        const float xv = x[bb * Ln + s];
                        float v = acc[mt][nt][r] + red[row * 64 + nt * 16 + lr] + xv * wv + bs;
                        H0wr[(size_t)bb * Hn + n] = f2bf(fast_tanh(v));
                    }
            }
        }
    } else {
        // ================= FC(t = s-2), split-K across waves ==============
        if (s < 2) return;
        const int t = s - 2;
        const int bBase = (bid - 1024) * 64;
        const int k0 = wave * 512;
        const unsigned short* Ag = H1rd;
        const unsigned short* Bg = fcWb;

        f32x4 acc[4][6];
#pragma unroll
        for (int i = 0; i < 4; ++i)
#pragma unroll
            for (int j = 0; j < 6; ++j) acc[i][j] = (f32x4){0.f, 0.f, 0.f, 0.f};

#pragma unroll
        for (int c = 0; c < 4; ++c)
            async16(Ag + (size_t)(bBase + c * 16 + srow) * Hn + k0 + scol, Al + c * 512);
#pragma unroll
        for (int c = 0; c < 6; ++c)
            async16(Bg + (size_t)(c * 16 + srow) * Hn + k0 + scol, Bl + c * 512);
        int buf = 0;
        for (int it = 0; it < 16; ++it) {
            __syncthreads();
            if (it + 1 < 16) {
                const int kt = k0 + (it + 1) * 32;
#pragma unroll
                for (int c = 0; c < 4; ++c)
                    async16(Ag + (size_t)(bBase + c * 16 + srow) * Hn + kt + scol,
                            Al + (buf ^ 1) * 2048 + c * 512);
#pragma unroll
                for (int c = 0; c < 6; ++c)
                    async16(Bg + (size_t)(c * 16 + srow) * Hn + kt + scol,
                            Bl + (buf ^ 1) * 3072 + c * 512);
            }
            bf16x8 a[4], b[6];
#pragma unroll
            for (int i = 0; i < 4; ++i)
                a[i] = *(const bf16x8*)(Al + buf * 2048 + (i * 16 + lr) * 32 + lq * 8);
#pragma unroll
            for (int i = 0; i < 6; ++i)
                b[i] = *(const bf16x8*)(Bl + buf * 3072 + (i * 16 + lr) * 32 + lq * 8);
#pragma unroll
            for (int mt = 0; mt < 4; ++mt)
#pragma unroll
                for (int nt = 0; nt < 6; ++nt)
                    acc[mt][nt] = __builtin_amdgcn_mfma_f32_16x16x32_bf16(
                        a[mt], b[nt], acc[mt][nt], 0, 0, 0);
            buf ^= 1;
        }
        __syncthreads();
        if (wave == 1) {
#pragma unroll
            for (int mt = 0; mt < 4; ++mt)
#pragma unroll
                for (int nt = 0; nt < 6; ++nt)
#pragma unroll
                    for (int r = 0; r < 4; ++r)
                        red[(mt * 16 + lq * 4 + r) * 96 + nt * 16 + lr] = acc[mt][nt][r];
        }
        __syncthreads();
        if (wave == 0) {
#pragma unroll
            for (int mt = 0; mt < 4; ++mt)
#pragma unroll
                for (int r = 0; r < 4; ++r) {
                    const int row = mt * 16 + lq * 4 + r;
                    const size_t o = (size_t)(bBase + row) * (Ln * Vn) + (size_t)t * Vn;
#pragma unroll
                    for (int nt = 0; nt < 6; ++nt) {
                        const int v = nt * 16 + lr;
                        out[o + v] = acc[mt][nt][r] + red[row * 96 + v] + fcb[v];
                    }
                }
        }
    }
}

// ---------------------------------------------------------------------------
__global__ void f32_to_bf16(const float* __restrict__ in,
                            unsigned short* __restrict__ out, int n)
{
    int i = blockIdx.x * blockDim.x + threadIdx.x;
    int stride = gridDim.x * blockDim.x;
    for (; i < n; i += stride) out[i] = f2bf(in[i]);
}

__global__ void hidden_out(const unsigned short* __restrict__ h0,
                           const unsigned short* __restrict__ h1,
                           float* __restrict__ out)
{
    int i = blockIdx.x * 256 + threadIdx.x;
    out[i] = bf2f(h0[i]);
    out[(size_t)Bn * Hn + i] = bf2f(h1[i]);
}

// ---------------------------------------------------------------------------
// Sequential probability adjustment (verified rounds 1-2). One wave per row.
// ---------------------------------------------------------------------------
__device__ __forceinline__ int wave_argmax(float v0, float v1, int lane)
{
    float bv = v0;
    int bi = lane;
    if (v1 > bv) { bv = v1; bi = 64 + lane; }
#pragma unroll
    for (int off = 32; off > 0; off >>= 1) {
        float ov = __shfl_xor(bv, off);
        int oi = __shfl_xor(bi, off);
        if (ov > bv || (ov == bv && oi < bi)) { bv = ov; bi = oi; }
    }
    return bi;
}

__global__ __launch_bounds__(256) void adjust_kernel(float* __restrict__ out)
{
    const int gtid = blockIdx.x * 256 + threadIdx.x;
    const int b = gtid >> 6;
    const int lane = threadIdx.x & 63;
    if (b >= Bn) return;
    float* row = out + (size_t)b * (Ln * Vn);

    float v0 = row[lane];
    float v1 = (lane < 32) ? row[64 + lane] : -1e30f;
    int prev_arg = wave_argmax(v0, v1, lane);

    for (int t = 1; t < Ln; ++t) {
        float* r = row + t * Vn;
        v0 = r[lane];
        v1 = (lane < 32) ? r[64 + lane] : -1e30f;
        int cur_arg = wave_argmax(v0, v1, lane);
        bool cond_u = (prev_arg == 0) && (cur_arg != 1);
        if (cond_u && lane == 1) v0 += 0.5f;
        bool cond_q = (t == Ln - 1) && (cur_arg == 0);
        if (cond_q && lane == 0) v0 -= 0.5f;
        r[lane] = v0;
        if (lane < 32) r[64 + lane] = v1;
        prev_arg = wave_argmax(v0, v1, lane);
    }
}

// ---------------------------------------------------------------------------
extern "C" void kernel_launch(void* const* d_in, const int* in_sizes, int n_in,
                              void* d_out, int out_size, void* d_ws, size_t ws_size,
                              hipStream_t stream)
{
    const float* x    = (const float*)d_in[0];
    const float* w0ih = (const float*)d_in[1];
    const float* W0   = (const float*)d_in[2];
    const float* b0i  = (const float*)d_in[3];
    const float* b0h  = (const float*)d_in[4];
    const float* W1i  = (const float*)d_in[5];
    const float* W1h  = (const float*)d_in[6];
    const float* b1i  = (const float*)d_in[7];
    const float* b1h  = (const float*)d_in[8];
    const float* fcW  = (const float*)d_in[9];
    const float* fcb  = (const float*)d_in[10];
    float* out = (float*)d_out;

    const size_t HH = (size_t)Hn * Hn;
    const size_t BH = (size_t)Bn * Hn;
    unsigned short* ws = (unsigned short*)d_ws;
    unsigned short* W0b  = ws;
    unsigned short* W1ib = ws + HH;
    unsigned short* W1hb = ws + 2 * HH;
    unsigned short* fcWb = ws + 3 * HH;
    unsigned short* H0[2] = { ws + 4 * HH,          ws + 4 * HH + BH };
    unsigned short* H1[2] = { ws + 4 * HH + 2 * BH, ws + 4 * HH + 3 * BH };

    // h0(-1) lives in H0[0], h1(-1) in H1[0] (read at s=0 / s=1): zero them.
    hipMemsetAsync(H0[0], 0, BH * sizeof(unsigned short), stream);
    hipMemsetAsync(H1[0], 0, BH * sizeof(unsigned short), stream);

    f32_to_bf16<<<dim3(512), dim3(256), 0, stream>>>(W0,  W0b,  (int)HH);
    f32_to_bf16<<<dim3(512), dim3(256), 0, stream>>>(W1i, W1ib, (int)HH);
    f32_to_bf16<<<dim3(512), dim3(256), 0, stream>>>(W1h, W1hb, (int)HH);
    f32_to_bf16<<<dim3(64),  dim3(256), 0, stream>>>(fcW, fcWb, Vn * Hn);

    // Launch s computes: L0(s) [s<=95], L1(s-1) [s>=1], FC(s-2) [s>=2].
    // h0(t) lives in H0[(t+1)&1]; h1(t) in H1[(t+1)&1].
    for (int s = 0; s <= 97; ++s) {
        fused_step<<<dim3(1056), dim3(128), 0, stream>>>(
            s,
            H0[s & 1], H0[(s + 1) & 1],          // L0 read / write
            H1[(s + 1) & 1], H1[s & 1],          // h1(s-2) read / h1(s-1) write
            W0b, W1ib, W1hb, fcWb,
            w0ih, b0i, b0h, b1i, b1h, fcb, x, out);
    }

    adjust_kernel<<<dim3(512), dim3(256), 0, stream>>>(out);

    // final states: h0(95) = H0[0], h1(95) = H1[0]
    hidden_out<<<dim3((int)(BH / 256)), dim3(256), 0, stream>>>(
        H0[0], H1[0], out + (size_t)Bn * Ln * Vn);
}